// Round 1
// baseline (456.090 us; speedup 1.0000x reference)
//
#include <hip/hip_runtime.h>

// Problem: x[T][E] f32, W[E][O] f32, bias[O] f32, lengths[B] int32.
// out[B][O] = (segment_mean(x, lengths) @ W) + bias
// T=131072, E=2048, O=1024, B=16 (derived at launch from in_sizes).

#define E_DIM 2048
#define O_DIM 1024
#define R_CHUNK 128   // rows per partial-sum chunk

// ---------------------------------------------------------------------------
// Phase 0: prefix-scan lengths -> meta[0..B): end offsets, meta[B..2B): chunk base
// ---------------------------------------------------------------------------
__global__ void setup_meta(const int* __restrict__ lengths, int Bn, int* __restrict__ meta) {
    int t = threadIdx.x;
    int len = (t < Bn) ? lengths[t] : 0;
    int nch = (t < Bn) ? (len + R_CHUNK - 1) / R_CHUNK : 0;
    int offs = len, cbase = nch;
    // inclusive wave scan (64 lanes, Bn <= 64)
    for (int d = 1; d < 64; d <<= 1) {
        int o2 = __shfl_up(offs, d);
        int c2 = __shfl_up(cbase, d);
        if (t >= d) { offs += o2; cbase += c2; }
    }
    if (t < Bn) {
        meta[t]      = offs;          // inclusive end offset of segment t
        meta[Bn + t] = cbase - nch;   // exclusive chunk base of segment t
    }
}

// ---------------------------------------------------------------------------
// Phase 1: per-(chunk, segment) partial column sums.
// grid = (maxChunks, B), block = 256. Block (c,b) sums rows
// [start_b + c*R_CHUNK, min(start_b + (c+1)*R_CHUNK, end_b)) over all E cols.
// ---------------------------------------------------------------------------
__global__ __launch_bounds__(256) void seg_partial(const float* __restrict__ x,
                                                   const int* __restrict__ meta,
                                                   int Bn,
                                                   float* __restrict__ partial) {
    const int b = blockIdx.y;
    const int c = blockIdx.x;
    const int s = (b == 0) ? 0 : meta[b - 1];
    const int e = meta[b];
    const int r0 = s + c * R_CHUNK;
    if (r0 >= e) return;                    // chunk beyond this segment
    const int r1 = min(r0 + R_CHUNK, e);
    const int gchunk = meta[Bn + b] + c;    // compact partial row index

    const int tx = threadIdx.x;
    float4 a0 = {0.f, 0.f, 0.f, 0.f};
    float4 a1 = {0.f, 0.f, 0.f, 0.f};
    const float* p = x + (size_t)r0 * E_DIM + tx * 4;
    for (int r = r0; r < r1; ++r) {
        float4 v0 = *(const float4*)(p);
        float4 v1 = *(const float4*)(p + 1024);
        a0.x += v0.x; a0.y += v0.y; a0.z += v0.z; a0.w += v0.w;
        a1.x += v1.x; a1.y += v1.y; a1.z += v1.z; a1.w += v1.w;
        p += E_DIM;
    }
    float* dst = partial + (size_t)gchunk * E_DIM + tx * 4;
    *(float4*)(dst)        = a0;
    *(float4*)(dst + 1024) = a1;
}

// ---------------------------------------------------------------------------
// Phase 2: reduce partial chunks -> means[b][e] (fixed order => deterministic)
// grid = (E/1024, B), block = 256, thread handles one float4.
// ---------------------------------------------------------------------------
__global__ __launch_bounds__(256) void reduce_means(const float* __restrict__ partial,
                                                    const int* __restrict__ meta,
                                                    const int* __restrict__ lengths,
                                                    int Bn,
                                                    float* __restrict__ means) {
    const int b   = blockIdx.y;
    const int col = blockIdx.x * 1024 + threadIdx.x * 4;
    const int cb  = meta[Bn + b];
    const int len = lengths[b];
    const int nch = (len + R_CHUNK - 1) / R_CHUNK;

    float4 acc = {0.f, 0.f, 0.f, 0.f};
    const float* p = partial + (size_t)cb * E_DIM + col;
    for (int c = 0; c < nch; ++c) {
        float4 v = *(const float4*)p;
        acc.x += v.x; acc.y += v.y; acc.z += v.z; acc.w += v.w;
        p += E_DIM;
    }
    const float inv = 1.0f / (float)len;
    acc.x *= inv; acc.y *= inv; acc.z *= inv; acc.w *= inv;
    *(float4*)(means + (size_t)b * E_DIM + col) = acc;
}

// ---------------------------------------------------------------------------
// Phase 3: out[b][o] = dot(means[b][:], W[:][o]) + bias[o]
// grid = (O/256, B), block = 256. means row staged in LDS (8 KB).
// W rows are read coalesced (256 consecutive floats per e).
// ---------------------------------------------------------------------------
__global__ __launch_bounds__(256) void gemm_out(const float* __restrict__ means,
                                                const float* __restrict__ W,
                                                const float* __restrict__ bias,
                                                float* __restrict__ out) {
    const int b = blockIdx.y;
    const int o = blockIdx.x * 256 + threadIdx.x;

    __shared__ float m_lds[E_DIM];
    const float4* msrc = (const float4*)(means + (size_t)b * E_DIM);
    for (int i = threadIdx.x; i < E_DIM / 4; i += 256)
        ((float4*)m_lds)[i] = msrc[i];
    __syncthreads();

    float acc = 0.f;
    const float* wp = W + o;
#pragma unroll 8
    for (int e = 0; e < E_DIM; ++e)
        acc += m_lds[e] * wp[(size_t)e * O_DIM];

    out[b * O_DIM + o] = acc + bias[o];
}

// ---------------------------------------------------------------------------
extern "C" void kernel_launch(void* const* d_in, const int* in_sizes, int n_in,
                              void* d_out, int out_size, void* d_ws, size_t ws_size,
                              hipStream_t stream) {
    const float* x       = (const float*)d_in[0];
    const float* W       = (const float*)d_in[1];
    const float* bias    = (const float*)d_in[2];
    const int*   lengths = (const int*)d_in[3];

    const int Bn = in_sizes[3];                 // 16
    const int On = in_sizes[2];                 // 1024
    const int En = in_sizes[1] / On;            // 2048
    const int Tn = in_sizes[0] / En;            // 131072
    (void)En; (void)out_size; (void)n_in; (void)ws_size;

    const int maxChunks = (Tn + R_CHUNK - 1) / R_CHUNK;       // 1024
    const int maxTotalChunks = maxChunks + Bn;                // compact partial rows bound

    // workspace layout
    int*   meta    = (int*)d_ws;                                           // 2*Bn ints
    float* partial = (float*)((char*)d_ws + 256);                          // [maxTotalChunks][E]
    float* means   = partial + (size_t)maxTotalChunks * E_DIM;             // [Bn][E]

    setup_meta<<<1, 64, 0, stream>>>(lengths, Bn, meta);

    dim3 g1(maxChunks, Bn);
    seg_partial<<<g1, 256, 0, stream>>>(x, meta, Bn, partial);

    dim3 g2(E_DIM / 1024, Bn);
    reduce_means<<<g2, 256, 0, stream>>>(partial, meta, lengths, Bn, means);

    dim3 g3(On / 256, Bn);
    gemm_out<<<g3, 256, 0, stream>>>(means, W, bias, (float*)d_out);
}

// Round 2
// 217.138 us; speedup vs baseline: 2.1005x; 2.1005x over previous
//
#include <hip/hip_runtime.h>

// Problem: x[T][E] f32, W[E][O] f32, bias[O] f32, lengths[B] int32.
// out[B][O] = (segment_mean(x, lengths) @ W) + bias
// T=131072, E=2048, O=1024, B=16 (derived at launch from in_sizes).

#define E_DIM 2048
#define O_DIM 1024
#define R_CHUNK 128   // rows per partial-sum chunk

typedef float v4f __attribute__((ext_vector_type(4)));

// ---------------------------------------------------------------------------
// Phase 1: per-chunk partial column sums, compact 1D grid.
// Block g handles compact chunk g; segment mapping derived in-block from
// lengths (16 ints, L2-hot). Each block sums <=128 rows over all E cols.
// ---------------------------------------------------------------------------
__global__ __launch_bounds__(256) void seg_partial(const float* __restrict__ x,
                                                   const int* __restrict__ lengths,
                                                   int Bn,
                                                   float* __restrict__ partial) {
    __shared__ int s_start[65];
    __shared__ int s_cbase[65];
    if (threadIdx.x == 0) {
        int off = 0, cb = 0;
        for (int i = 0; i < Bn; ++i) {
            s_start[i] = off; s_cbase[i] = cb;
            const int l = lengths[i];
            off += l; cb += (l + R_CHUNK - 1) / R_CHUNK;
        }
        s_start[Bn] = off; s_cbase[Bn] = cb;
    }
    __syncthreads();

    const int g = blockIdx.x;
    if (g >= s_cbase[Bn]) return;              // beyond total chunk count
    int b = 0;
    while (g >= s_cbase[b + 1]) ++b;           // <=15 iterations, LDS-hot
    const int r0 = s_start[b] + (g - s_cbase[b]) * R_CHUNK;
    const int r1 = min(r0 + R_CHUNK, s_start[b + 1]);

    const int tx = threadIdx.x;
    v4f a0 = {0.f, 0.f, 0.f, 0.f};
    v4f a1 = {0.f, 0.f, 0.f, 0.f};
    const v4f* p = (const v4f*)(x + (size_t)r0 * E_DIM + tx * 4);
#pragma unroll 4
    for (int r = r0; r < r1; ++r) {
        v4f v0 = __builtin_nontemporal_load(p);        // x is read exactly once
        v4f v1 = __builtin_nontemporal_load(p + 256);  // +1024 floats
        a0 += v0;
        a1 += v1;
        p += E_DIM / 4;
    }
    v4f* dst = (v4f*)(partial + (size_t)g * E_DIM + tx * 4);
    dst[0]   = a0;
    dst[256] = a1;
}

// ---------------------------------------------------------------------------
// Phase 2: reduce partial chunks -> means[b][e] (fixed order => deterministic)
// grid = (E/1024, B), block = 256, thread handles one float4. Unroll 8 so
// ~8 independent 16B loads are in flight (the loop is latency-bound).
// ---------------------------------------------------------------------------
__global__ __launch_bounds__(256) void reduce_means(const float* __restrict__ partial,
                                                    const int* __restrict__ lengths,
                                                    int Bn,
                                                    float* __restrict__ means) {
    __shared__ int s_cb, s_nch, s_len;
    if (threadIdx.x == 0) {
        const int b = blockIdx.y;
        int cb = 0;
        for (int i = 0; i < b; ++i) cb += (lengths[i] + R_CHUNK - 1) / R_CHUNK;
        s_cb = cb;
        s_len = lengths[b];
        s_nch = (s_len + R_CHUNK - 1) / R_CHUNK;
    }
    __syncthreads();

    const int col = blockIdx.x * 1024 + threadIdx.x * 4;
    const int nch = s_nch;
    v4f acc = {0.f, 0.f, 0.f, 0.f};
    const v4f* p = (const v4f*)(partial + (size_t)s_cb * E_DIM + col);
#pragma unroll 8
    for (int c = 0; c < nch; ++c) {            // fixed order: deterministic
        acc += *p;
        p += E_DIM / 4;
    }
    acc *= (1.0f / (float)s_len);
    *(v4f*)(means + (size_t)blockIdx.y * E_DIM + col) = acc;
}

// ---------------------------------------------------------------------------
// Phase 3: out[b][o] = dot(means[b][:], W[:][o]) + bias[o]
// grid = (O/64, B) = 256 blocks; block = 256 threads = 64 outputs x 4 e-groups.
// means row staged in LDS (broadcast reads, conflict-free); W reads coalesced
// 256B per wave. 4-way LDS reduce at the end.
// ---------------------------------------------------------------------------
__global__ __launch_bounds__(256) void gemm_out(const float* __restrict__ means,
                                                const float* __restrict__ W,
                                                const float* __restrict__ bias,
                                                float* __restrict__ out) {
    const int b      = blockIdx.y;
    const int olocal = threadIdx.x & 63;
    const int eg     = threadIdx.x >> 6;
    const int o      = blockIdx.x * 64 + olocal;

    __shared__ float m_lds[E_DIM];
    __shared__ float red[4][64];
    const v4f* msrc = (const v4f*)(means + (size_t)b * E_DIM);
    for (int i = threadIdx.x; i < E_DIM / 4; i += 256)
        ((v4f*)m_lds)[i] = msrc[i];
    __syncthreads();

    float acc = 0.f;
    const float* wp = W + (size_t)(eg * 512) * O_DIM + o;
    const float* mp = m_lds + eg * 512;
#pragma unroll 8
    for (int i = 0; i < 512; ++i)
        acc += mp[i] * wp[(size_t)i * O_DIM];

    red[eg][olocal] = acc;
    __syncthreads();
    if (eg == 0) {
        const float r = red[0][olocal] + red[1][olocal] + red[2][olocal]
                      + red[3][olocal] + bias[o];
        out[b * O_DIM + o] = r;
    }
}

// ---------------------------------------------------------------------------
extern "C" void kernel_launch(void* const* d_in, const int* in_sizes, int n_in,
                              void* d_out, int out_size, void* d_ws, size_t ws_size,
                              hipStream_t stream) {
    const float* x       = (const float*)d_in[0];
    const float* W       = (const float*)d_in[1];
    const float* bias    = (const float*)d_in[2];
    const int*   lengths = (const int*)d_in[3];

    const int Bn = in_sizes[3];                 // 16
    const int On = in_sizes[2];                 // 1024
    const int En = in_sizes[1] / On;            // 2048
    const int Tn = in_sizes[0] / En;            // 131072
    (void)En; (void)out_size; (void)n_in; (void)ws_size;

    const int maxChunks      = (Tn + R_CHUNK - 1) / R_CHUNK;  // 1024
    const int maxTotalChunks = maxChunks + Bn;                // compact upper bound

    // workspace layout
    float* partial = (float*)d_ws;                                  // [maxTotalChunks][E]
    float* means   = partial + (size_t)maxTotalChunks * E_DIM;      // [Bn][E]

    seg_partial<<<maxTotalChunks, 256, 0, stream>>>(x, lengths, Bn, partial);

    dim3 g2(E_DIM / 1024, Bn);
    reduce_means<<<g2, 256, 0, stream>>>(partial, lengths, Bn, means);

    dim3 g3(On / 64, Bn);
    gemm_out<<<g3, 256, 0, stream>>>(means, W, bias, (float*)d_out);
}

// Round 3
// 201.298 us; speedup vs baseline: 2.2657x; 1.0787x over previous
//
#include <hip/hip_runtime.h>

// Problem: x[T][E] f32, W[E][O] f32, bias[O] f32, lengths[B] int32.
// out[B][O] = (segment_mean(x, lengths) @ W) + bias
// T=131072, E=2048, O=1024, B=16 (derived at launch from in_sizes).
//
// Structure: (1) seg_partial: chunked column sums of x (the 1.07 GB stream —
// the entire roofline), 64-row chunks, 8 blocks/CU for max latency hiding.
// (2) reduce_p2: 8-way-split deterministic chunk reduction (256 blocks).
// (3) gemm_out: folds the 8-way partial sum + 1/len scale into LDS staging,
// then 64-o x 8-egroup dot with 4 independent accumulators.

#define E_DIM 2048
#define O_DIM 1024
#define R_CHUNK 64     // rows per partial-sum chunk (T/64 + B = 2064 blocks ~ 8/CU)
#define S_SPLIT 8      // phase-2 chunk-range split factor

typedef float v4f __attribute__((ext_vector_type(4)));

// ---------------------------------------------------------------------------
// Phase 1: per-chunk partial column sums, compact 1D grid, 32 waves/CU.
// Chunk->segment mapping computed redundantly per thread (16 ints, L1-hot;
// avoids LDS + barrier).
// ---------------------------------------------------------------------------
__global__ __launch_bounds__(256, 8) void seg_partial(const float* __restrict__ x,
                                                      const int* __restrict__ lengths,
                                                      int Bn,
                                                      float* __restrict__ partial) {
    const int g = blockIdx.x;
    int off = 0, cb = 0, r0 = 0, r1 = 0, found = 0;
    for (int i = 0; i < Bn; ++i) {
        const int l  = lengths[i];
        const int nc = (l + R_CHUNK - 1) / R_CHUNK;
        if (g < cb + nc) {
            r0 = off + (g - cb) * R_CHUNK;
            r1 = min(r0 + R_CHUNK, off + l);
            found = 1;
            break;
        }
        off += l; cb += nc;
    }
    if (!found) return;                       // beyond total chunk count

    const int tx = threadIdx.x;
    v4f a0 = {0.f, 0.f, 0.f, 0.f};
    v4f a1 = {0.f, 0.f, 0.f, 0.f};
    const v4f* p = (const v4f*)(x + (size_t)r0 * E_DIM + tx * 4);
#pragma unroll 4
    for (int r = r0; r < r1; ++r) {
        v4f v0 = __builtin_nontemporal_load(p);        // x read exactly once
        v4f v1 = __builtin_nontemporal_load(p + 256);  // +1024 floats
        a0 += v0;
        a1 += v1;
        p += E_DIM / 4;
    }
    v4f* dst = (v4f*)(partial + (size_t)g * E_DIM + tx * 4);
    dst[0]   = a0;
    dst[256] = a1;
}

// ---------------------------------------------------------------------------
// Phase 2: 8-way-split reduction of partial chunks -> p2[b][s][e].
// grid = (E/1024, B, S_SPLIT) = 256 blocks. Fixed order => deterministic.
// ---------------------------------------------------------------------------
__global__ __launch_bounds__(256) void reduce_p2(const float* __restrict__ partial,
                                                 const int* __restrict__ lengths,
                                                 int Bn,
                                                 float* __restrict__ p2) {
    const int b = blockIdx.y;
    const int s = blockIdx.z;
    int cb = 0;
    for (int i = 0; i < b; ++i) cb += (lengths[i] + R_CHUNK - 1) / R_CHUNK;
    const int nch = (lengths[b] + R_CHUNK - 1) / R_CHUNK;
    const int c0 = (nch * s) / S_SPLIT;
    const int c1 = (nch * (s + 1)) / S_SPLIT;

    const int col = blockIdx.x * 1024 + threadIdx.x * 4;
    v4f acc = {0.f, 0.f, 0.f, 0.f};
    const v4f* p = (const v4f*)(partial + (size_t)(cb + c0) * E_DIM + col);
#pragma unroll 8
    for (int c = c0; c < c1; ++c) {           // fixed order: deterministic
        acc += *p;
        p += E_DIM / 4;
    }
    *(v4f*)(p2 + ((size_t)(b * S_SPLIT + s)) * E_DIM + col) = acc;
}

// ---------------------------------------------------------------------------
// Phase 3: out[b][o] = dot(mean[b][:], W[:][o]) + bias[o]
// grid = (O/64, B) = 256 blocks; block = 512 = 64 outputs x 8 e-groups.
// Staging sums the 8 p2 rows and applies 1/len (no separate means kernel).
// 4 independent accumulators break the FMA dependency chain.
// ---------------------------------------------------------------------------
__global__ __launch_bounds__(512) void gemm_out(const float* __restrict__ p2,
                                                const float* __restrict__ W,
                                                const float* __restrict__ bias,
                                                const int* __restrict__ lengths,
                                                float* __restrict__ out) {
    const int b      = blockIdx.y;
    const int tx     = threadIdx.x;
    const int olocal = tx & 63;
    const int eg     = tx >> 6;                    // 8 e-groups of 256
    const int o      = blockIdx.x * 64 + olocal;

    __shared__ float m_lds[E_DIM];
    __shared__ float red[S_SPLIT][64];

    // stage mean row: each thread sums one float4 across the 8 splits, scales
    {
        const float inv = 1.0f / (float)lengths[b];
        const int col = tx * 4;                    // 512 threads x 4 = 2048
        const v4f* ps = (const v4f*)(p2 + (size_t)b * S_SPLIT * E_DIM + col);
        v4f m = {0.f, 0.f, 0.f, 0.f};
#pragma unroll
        for (int s = 0; s < S_SPLIT; ++s)
            m += ps[s * (E_DIM / 4)];
        m *= inv;
        *(v4f*)(m_lds + col) = m;
    }
    __syncthreads();

    float a0 = 0.f, a1 = 0.f, a2 = 0.f, a3 = 0.f;
    const float* wp = W + (size_t)(eg * 256) * O_DIM + o;
    const float* mp = m_lds + eg * 256;
#pragma unroll 8
    for (int i = 0; i < 256; i += 4) {
        a0 += mp[i + 0] * wp[(size_t)(i + 0) * O_DIM];
        a1 += mp[i + 1] * wp[(size_t)(i + 1) * O_DIM];
        a2 += mp[i + 2] * wp[(size_t)(i + 2) * O_DIM];
        a3 += mp[i + 3] * wp[(size_t)(i + 3) * O_DIM];
    }
    red[eg][olocal] = (a0 + a1) + (a2 + a3);
    __syncthreads();

    if (tx < 64) {
        float r = bias[blockIdx.x * 64 + tx];
#pragma unroll
        for (int s = 0; s < S_SPLIT; ++s) r += red[s][tx];
        out[b * O_DIM + blockIdx.x * 64 + tx] = r;
    }
}

// ---------------------------------------------------------------------------
extern "C" void kernel_launch(void* const* d_in, const int* in_sizes, int n_in,
                              void* d_out, int out_size, void* d_ws, size_t ws_size,
                              hipStream_t stream) {
    const float* x       = (const float*)d_in[0];
    const float* W       = (const float*)d_in[1];
    const float* bias    = (const float*)d_in[2];
    const int*   lengths = (const int*)d_in[3];

    const int Bn = in_sizes[3];                 // 16
    const int On = in_sizes[2];                 // 1024
    const int En = in_sizes[1] / On;            // 2048
    const int Tn = in_sizes[0] / En;            // 131072
    (void)En; (void)out_size; (void)n_in; (void)ws_size;

    const int maxChunks      = (Tn + R_CHUNK - 1) / R_CHUNK;  // 2048
    const int maxTotalChunks = maxChunks + Bn;                // 2064

    // workspace layout
    float* partial = (float*)d_ws;                                  // [2064][E]
    float* p2      = partial + (size_t)maxTotalChunks * E_DIM;      // [B][S][E]

    seg_partial<<<maxTotalChunks, 256, 0, stream>>>(x, lengths, Bn, partial);

    dim3 g2(E_DIM / 1024, Bn, S_SPLIT);
    reduce_p2<<<g2, 256, 0, stream>>>(partial, lengths, Bn, p2);

    dim3 g3(On / 64, Bn);
    gemm_out<<<g3, 512, 0, stream>>>(p2, W, bias, lengths, (float*)d_out);
}